// Round 3
// baseline (567.634 us; speedup 1.0000x reference)
//
#include <hip/hip_runtime.h>
#include <hip/hip_bf16.h>
#include <cmath>
#include <cstdint>

typedef __bf16 bf16;
typedef __bf16 bf16x8 __attribute__((ext_vector_type(8)));
typedef __bf16 bf16x4 __attribute__((ext_vector_type(4)));
typedef float  f32x4  __attribute__((ext_vector_type(4)));

#define EMBED 1024
#define FFDIM 4096
#define BATCH 4
#define SEQ   2048
#define MTOK  (BATCH*SEQ)

// ---------------- workspace layout (byte offsets) ----------------
static constexpr size_t OFF_XPE_F32 = 0;              // 32MB f32 [8192][1024]
static constexpr size_t OFF_XPE_B   = 32ull << 20;    // 16MB bf16; reused as h_bf16
static constexpr size_t OFF_Q       = 48ull << 20;    // 16MB bf16
static constexpr size_t OFF_K       = 64ull << 20;    // 16MB bf16
static constexpr size_t OFF_VT     = 80ull << 20;     // 16MB bf16 [4][1024][2048]
static constexpr size_t OFF_T1      = 96ull << 20;    // 64MB bf16 [8192][4096]
static constexpr size_t OFF_ATTN    = 160ull << 20;   // 32MB f32; reused as Y f32
static constexpr size_t OFF_H       = 192ull << 20;   // 32MB f32
static constexpr size_t OFF_WQKVT   = 224ull << 20;   // 6MB bf16 [3072][1024]
static constexpr size_t OFF_W1T     = 230ull << 20;   // 8MB bf16 [4096][1024]
static constexpr size_t OFF_W2T     = 238ull << 20;   // 8MB bf16 [1024][4096]

// ---------------- PE add ----------------
__global__ __launch_bounds__(256) void pe_add_kernel(const float* __restrict__ x,
                                                     float* __restrict__ xf,
                                                     bf16* __restrict__ xb) {
  int idx  = blockIdx.x * 256 + threadIdx.x;
  int pair = idx & 511;
  int s    = idx >> 9;
  float div = __expf((float)(2 * pair) * (-9.210340371976184f / (float)EMBED));
  float ang = (float)s * div;
  float sv = sinf(ang), cv = cosf(ang);
#pragma unroll
  for (int b = 0; b < BATCH; ++b) {
    size_t base = ((size_t)(b * SEQ + s)) * EMBED + (size_t)pair * 2;
    float v0 = x[base] + sv;
    float v1 = x[base + 1] + cv;
    xf[base] = v0; xf[base + 1] = v1;
    xb[base] = (bf16)v0; xb[base + 1] = (bf16)v1;
  }
}

// ---------------- weight transpose fp32[K][N] -> bf16[N][K] ----------------
__global__ __launch_bounds__(256) void transpose_kernel(const float* __restrict__ W,
                                                        bf16* __restrict__ Wt,
                                                        int K, int N) {
  __shared__ float tile[32][33];
  int nb = blockIdx.x * 32, kb = blockIdx.y * 32;
  int tx = threadIdx.x, ty = threadIdx.y;   // 32x8
#pragma unroll
  for (int i = 0; i < 32; i += 8)
    tile[ty + i][tx] = W[(size_t)(kb + ty + i) * N + nb + tx];
  __syncthreads();
#pragma unroll
  for (int i = 0; i < 32; i += 8)
    Wt[(size_t)(nb + ty + i) * K + kb + tx] = (bf16)tile[tx][ty + i];
}

// ---------------- GEMM: C[M,N] = A[M,K] @ Bt[N,K]^T ----------------
// EPI 3: bf16 out, +bias, relu (FF1)   EPI 4: f32 out, +bias (FF2)
// EPI 6: fused QKV: col<1024 -> Q row-major, <2048 -> K row-major, else VT scatter
#define BM 128
#define BN 128
#define BK 64

__device__ __forceinline__ void gload_lds16(const void* g, void* l) {
  __builtin_amdgcn_global_load_lds((const __attribute__((address_space(1))) void*)g,
                                   (__attribute__((address_space(3))) void*)l, 16, 0, 0);
}

template <int EPI>
__global__ __launch_bounds__(256) void gemm_kernel(
    const bf16* __restrict__ A, const bf16* __restrict__ B,
    const float* __restrict__ bias, void* __restrict__ out,
    int K, int ldo, const float* bias2, const float* bias3, void* out2, void* out3) {
  __shared__ __align__(16) bf16 sA[BM][BK];
  __shared__ __align__(16) bf16 sB[BN][BK];

  // T1: bijective XCD-chunked swizzle + grouped raster
  const int gx = gridDim.x, gy = gridDim.y;
  int id = blockIdx.x + gx * blockIdx.y;
  const int n  = gx * gy;
  const int q  = n >> 3, r = n & 7;
  const int xcd = id & 7, pos = id >> 3;
  int lid = (xcd < r ? xcd * (q + 1) : r * (q + 1) + (xcd - r) * q) + pos;
  const int G = 16;
  const int ngrp = G * gy;
  const int grp = lid / ngrp;
  const int within = lid - grp * ngrp;
  const int gw = min(G, gx - grp * G);
  const int tx = grp * G + within % gw;
  const int ty = within / gw;

  const int tid  = threadIdx.x;
  const int wave = tid >> 6;
  const int lane = tid & 63;
  const int wm = wave >> 1, wn = wave & 1;
  const int rowBase = ty * BM;
  const int colBase = tx * BN;

  const int rA = tid >> 3;
  const int srcSlot = (tid & 7) ^ (rA & 7);
  const bf16* gA = A + (size_t)(rowBase + rA) * K + srcSlot * 8;
  const bf16* gB = B + (size_t)(colBase + rA) * K + srcSlot * 8;
  char* lA = (char*)&sA[0][0] + wave * 1024;
  char* lB = (char*)&sB[0][0] + wave * 1024;

  const f32x4 zero4 = {0.f, 0.f, 0.f, 0.f};
  f32x4 acc[4][4];
#pragma unroll
  for (int i = 0; i < 4; ++i)
#pragma unroll
    for (int j = 0; j < 4; ++j) acc[i][j] = zero4;

  const int lr = lane & 15;
  const int lx = lane & 7;
  const int q4 = lane >> 4;
  const char* bA = (const char*)&sA[0][0];
  const char* bB = (const char*)&sB[0][0];

  for (int kt = 0; kt < K; kt += BK) {
#pragma unroll
    for (int p = 0; p < 4; ++p) {
      gload_lds16(gA + (size_t)(p * 32) * K + kt, lA + p * 4096);
      gload_lds16(gB + (size_t)(p * 32) * K + kt, lB + p * 4096);
    }
    __syncthreads();
#pragma unroll
    for (int kk = 0; kk < 2; ++kk) {
      bf16x8 fa[4], fb[4];
      const int slot = kk * 4 + q4;
      const int sws = (slot ^ lx) << 4;
#pragma unroll
      for (int i = 0; i < 4; ++i)
        fa[i] = *(const bf16x8*)(bA + (wm * 64 + i * 16 + lr) * 128 + sws);
#pragma unroll
      for (int j = 0; j < 4; ++j)
        fb[j] = *(const bf16x8*)(bB + (wn * 64 + j * 16 + lr) * 128 + sws);
#pragma unroll
      for (int i = 0; i < 4; ++i)
#pragma unroll
        for (int j = 0; j < 4; ++j)
          acc[i][j] = __builtin_amdgcn_mfma_f32_16x16x32_bf16(fa[i], fb[j], acc[i][j], 0, 0, 0);
    }
    __syncthreads();
  }

  // epilogue: C/D layout col = lane&15, row = (lane>>4)*4 + reg
  const int lrow4 = (lane >> 4) * 4;
#pragma unroll
  for (int j = 0; j < 4; ++j) {
    const int col = colBase + wn * 64 + j * 16 + lr;
#pragma unroll
    for (int i = 0; i < 4; ++i) {
      const int row0 = rowBase + wm * 64 + i * 16 + lrow4;
      if constexpr (EPI == 6) {
        const int cb = col >> 10;       // 0:Q 1:K 2:V  (uniform per block)
        const int c  = col & 1023;
        const float bv = (cb == 0 ? bias : (cb == 1 ? bias2 : bias3))[c];
        if (cb == 2) {
          const int b_ = row0 >> 11;
          const int s_ = row0 & (SEQ - 1);
          bf16x4 pv;
#pragma unroll
          for (int rr = 0; rr < 4; ++rr) pv[rr] = (bf16)(acc[i][j][rr] + bv);
          *(bf16x4*)((bf16*)out3 + ((size_t)b_ * EMBED + c) * SEQ + s_) = pv;
        } else {
          bf16* dst = (cb == 0 ? (bf16*)out : (bf16*)out2);
#pragma unroll
          for (int rr = 0; rr < 4; ++rr)
            dst[(size_t)(row0 + rr) * EMBED + c] = (bf16)(acc[i][j][rr] + bv);
        }
      } else {
        const float bv = bias[col];
#pragma unroll
        for (int rr = 0; rr < 4; ++rr) {
          const int row = row0 + rr;
          const float v = acc[i][j][rr];
          if constexpr (EPI == 3) {
            float t = v + bv;
            ((bf16*)out)[(size_t)row * ldo + col] = (bf16)(t > 0.f ? t : 0.f);
          } else if constexpr (EPI == 4) {
            ((float*)out)[(size_t)row * ldo + col] = v + bv;
          }
        }
      }
    }
  }
}

// ---------------- fused flash attention ----------------
// 256 blocks (1/CU), 8 waves, QBLK=32 rows, KVBLK=256.
// Swapped QK^T: S^T[kv][q] = mfma(K, Q). PV: O^T[d][q] = mfma(VT, P_lds).
#define QBLK 32
#define KVBLK 256

__global__ __launch_bounds__(512) void flash_kernel(const bf16* __restrict__ Qg,
                                                    const bf16* __restrict__ Kg,
                                                    const bf16* __restrict__ Vt,
                                                    float* __restrict__ attn) {
  __shared__ __align__(16) bf16 Qs[QBLK * EMBED];   // 64KB, XOR-swizzled rows
  __shared__ __align__(16) bf16 Ps[QBLK * KVBLK];   // 16KB [q][kv], swizzled
  __shared__ float red[8 * 32];
  __shared__ float rsum[8 * 32];
  __shared__ float m_s[32], a_s[32], l_s[32];

  const int bid = blockIdx.x;
  const int lid = (bid & 7) * 32 + (bid >> 3);   // XCD-chunked
  const int b   = lid >> 6;
  const int qt  = lid & 63;
  const bf16* Qp = Qg + ((size_t)b * SEQ + qt * QBLK) * EMBED;
  const bf16* Kp = Kg + (size_t)b * SEQ * EMBED;
  const bf16* Vp = Vt + (size_t)b * EMBED * SEQ;

  const int tid = threadIdx.x;
  const int w = tid >> 6, lane = tid & 63;
  const int lr = lane & 15, g = lane >> 4;

  // stage Q (pre-swizzled source; LDS dest linear per rule 21)
#pragma unroll
  for (int p = 0; p < 8; ++p) {
    const int row = p * 4 + (w >> 1);
    const int chunk = ((w & 1) * 64 + lane) ^ (row & 7);
    gload_lds16(Qp + (size_t)row * EMBED + chunk * 8,
                (char*)Qs + p * 8192 + w * 1024);
  }
  if (tid < 32) { m_s[tid] = -1e30f; l_s[tid] = 0.f; }

  const f32x4 zero4 = {0.f, 0.f, 0.f, 0.f};
  f32x4 o[8][2];
#pragma unroll
  for (int mm = 0; mm < 8; ++mm) { o[mm][0] = zero4; o[mm][1] = zero4; }
  __syncthreads();

  for (int kv0 = 0; kv0 < SEQ; kv0 += KVBLK) {
    // ---- QK^T (swapped): s[m=kv-frag][n=q-frag] ----
    f32x4 s[2][2];
    s[0][0] = zero4; s[0][1] = zero4; s[1][0] = zero4; s[1][1] = zero4;
    const bf16* Kb_ = Kp + (size_t)(kv0 + w * 32) * EMBED;
    const int q0r = lr, q1r = 16 + lr;
#pragma unroll 8
    for (int kk = 0; kk < 32; ++kk) {
      const int dk = kk * 32 + g * 8;
      const int ch = kk * 4 + g;
      bf16x8 a0 = *(const bf16x8*)(Kb_ + (size_t)lr * EMBED + dk);
      bf16x8 a1 = *(const bf16x8*)(Kb_ + (size_t)(16 + lr) * EMBED + dk);
      bf16x8 b0 = *(const bf16x8*)((char*)Qs + q0r * 2048 + ((ch ^ (q0r & 7)) << 4));
      bf16x8 b1 = *(const bf16x8*)((char*)Qs + q1r * 2048 + ((ch ^ (q1r & 7)) << 4));
      s[0][0] = __builtin_amdgcn_mfma_f32_16x16x32_bf16(a0, b0, s[0][0], 0, 0, 0);
      s[0][1] = __builtin_amdgcn_mfma_f32_16x16x32_bf16(a0, b1, s[0][1], 0, 0, 0);
      s[1][0] = __builtin_amdgcn_mfma_f32_16x16x32_bf16(a1, b0, s[1][0], 0, 0, 0);
      s[1][1] = __builtin_amdgcn_mfma_f32_16x16x32_bf16(a1, b1, s[1][1], 0, 0, 0);
    }
    // ---- scale + per-q chunk max (this wave's 32 kv) ----
    float mx[2];
#pragma unroll
    for (int nn = 0; nn < 2; ++nn) {
      float m0 = -1e30f;
#pragma unroll
      for (int mm = 0; mm < 2; ++mm)
#pragma unroll
        for (int rr = 0; rr < 4; ++rr) {
          s[mm][nn][rr] *= 0.03125f;
          m0 = fmaxf(m0, s[mm][nn][rr]);
        }
      m0 = fmaxf(m0, __shfl_xor(m0, 16));
      m0 = fmaxf(m0, __shfl_xor(m0, 32));
      mx[nn] = m0;
    }
    if (g == 0) { red[w * 32 + lr] = mx[0]; red[w * 32 + 16 + lr] = mx[1]; }
    __syncthreads();                                   // (1) red ready
    if (tid < 32) {
      float cm = red[tid];
#pragma unroll
      for (int ww = 1; ww < 8; ++ww) cm = fmaxf(cm, red[ww * 32 + tid]);
      const float mo = m_s[tid];
      const float mn = fmaxf(mo, cm);
      m_s[tid] = mn;
      a_s[tid] = __expf(mo - mn);
    }
    __syncthreads();                                   // (2) m_s/a_s ready
    // ---- P = exp(s - m), rowsum, pack to Ps[q][kv] ----
    float rs[2];
#pragma unroll
    for (int nn = 0; nn < 2; ++nn) {
      const int qq = nn * 16 + lr;
      const float mq = m_s[qq];
      float sum = 0.f;
#pragma unroll
      for (int mm = 0; mm < 2; ++mm) {
        float p0 = __expf(s[mm][nn][0] - mq);
        float p1 = __expf(s[mm][nn][1] - mq);
        float p2 = __expf(s[mm][nn][2] - mq);
        float p3 = __expf(s[mm][nn][3] - mq);
        sum += (p0 + p1) + (p2 + p3);
        bf16x4 pk;
        pk[0] = (bf16)p0; pk[1] = (bf16)p1; pk[2] = (bf16)p2; pk[3] = (bf16)p3;
        const int kv = w * 32 + mm * 16 + g * 4;
        const int ch = kv >> 3;
        *(bf16x4*)((char*)Ps + qq * 512 + ((ch ^ (qq & 7)) << 4) + ((g & 1) << 3)) = pk;
      }
      sum += __shfl_xor(sum, 16);
      sum += __shfl_xor(sum, 32);
      rs[nn] = sum;
    }
    if (g == 0) { rsum[w * 32 + lr] = rs[0]; rsum[w * 32 + 16 + lr] = rs[1]; }
    // rescale O by alpha(q)
    const float al0 = a_s[lr], al1 = a_s[16 + lr];
#pragma unroll
    for (int mm = 0; mm < 8; ++mm)
#pragma unroll
      for (int rr = 0; rr < 4; ++rr) { o[mm][0][rr] *= al0; o[mm][1][rr] *= al1; }
    __syncthreads();                                   // (3) Ps + rsum ready
    if (tid < 32) {
      float t = l_s[tid] * a_s[tid];
#pragma unroll
      for (int ww = 0; ww < 8; ++ww) t += rsum[ww * 32 + tid];
      l_s[tid] = t;
    }
    // ---- PV: O^T[d][q] += VT[d][kv] · P[q][kv] ----
    const bf16* Vb = Vp + (size_t)(w * 128) * SEQ + kv0;
#pragma unroll 2
    for (int kk = 0; kk < 8; ++kk) {
      const int kvk = kk * 32 + g * 8;
      const int ch = kk * 4 + g;
      bf16x8 pb0 = *(const bf16x8*)((char*)Ps + q0r * 512 + ((ch ^ (q0r & 7)) << 4));
      bf16x8 pb1 = *(const bf16x8*)((char*)Ps + q1r * 512 + ((ch ^ (q1r & 7)) << 4));
#pragma unroll
      for (int mm = 0; mm < 8; ++mm) {
        bf16x8 av = *(const bf16x8*)(Vb + (size_t)(mm * 16 + lr) * SEQ + kvk);
        o[mm][0] = __builtin_amdgcn_mfma_f32_16x16x32_bf16(av, pb0, o[mm][0], 0, 0, 0);
        o[mm][1] = __builtin_amdgcn_mfma_f32_16x16x32_bf16(av, pb1, o[mm][1], 0, 0, 0);
      }
    }
    __syncthreads();                                   // (4) Ps consumed, l_s done
  }

  // ---- epilogue: O = O^T / l, direct f32x4 stores (4 consecutive d per reg) ----
  const float li0 = 1.0f / l_s[lr];
  const float li1 = 1.0f / l_s[16 + lr];
  float* outb = attn + ((size_t)b * SEQ + qt * QBLK) * EMBED;
#pragma unroll
  for (int mm = 0; mm < 8; ++mm) {
    const int d = w * 128 + mm * 16 + g * 4;
    f32x4 v0, v1;
#pragma unroll
    for (int rr = 0; rr < 4; ++rr) { v0[rr] = o[mm][0][rr] * li0; v1[rr] = o[mm][1][rr] * li1; }
    *(f32x4*)(outb + (size_t)lr * EMBED + d) = v0;
    *(f32x4*)(outb + (size_t)(16 + lr) * EMBED + d) = v1;
  }
}

// ---------------- LayerNorm: out = LN(X + R) * g + b ----------------
__global__ __launch_bounds__(256) void ln_kernel(const float* __restrict__ X,
                                                 const float* __restrict__ R,
                                                 const float* __restrict__ gm,
                                                 const float* __restrict__ bt,
                                                 float* __restrict__ of,
                                                 bf16* __restrict__ ob) {
  const size_t row = blockIdx.x;
  const int t = threadIdx.x;
  float4 xv = ((const float4*)(X + row * EMBED))[t];
  float4 rv = ((const float4*)(R + row * EMBED))[t];
  float4 v;
  v.x = xv.x + rv.x; v.y = xv.y + rv.y; v.z = xv.z + rv.z; v.w = xv.w + rv.w;
  float s  = v.x + v.y + v.z + v.w;
  float ss = v.x * v.x + v.y * v.y + v.z * v.z + v.w * v.w;
#pragma unroll
  for (int o = 32; o; o >>= 1) { s += __shfl_xor(s, o); ss += __shfl_xor(ss, o); }
  __shared__ float red[8];
  const int w = t >> 6;
  if ((t & 63) == 0) { red[w] = s; red[4 + w] = ss; }
  __syncthreads();
  s  = red[0] + red[1] + red[2] + red[3];
  ss = red[4] + red[5] + red[6] + red[7];
  const float mu  = s * (1.0f / EMBED);
  const float inv = rsqrtf(ss * (1.0f / EMBED) - mu * mu + 1e-5f);
  float4 gv = ((const float4*)gm)[t];
  float4 bv = ((const float4*)bt)[t];
  float4 o4;
  o4.x = (v.x - mu) * inv * gv.x + bv.x;
  o4.y = (v.y - mu) * inv * gv.y + bv.y;
  o4.z = (v.z - mu) * inv * gv.z + bv.z;
  o4.w = (v.w - mu) * inv * gv.w + bv.w;
  if (of) ((float4*)(of + row * EMBED))[t] = o4;
  if (ob) {
    bf16x4 p;
    p[0] = (bf16)o4.x; p[1] = (bf16)o4.y; p[2] = (bf16)o4.z; p[3] = (bf16)o4.w;
    *(bf16x4*)(ob + row * EMBED + (size_t)t * 4) = p;
  }
}

// ---------------- launch ----------------
extern "C" void kernel_launch(void* const* d_in, const int* in_sizes, int n_in,
                              void* d_out, int out_size, void* d_ws, size_t ws_size,
                              hipStream_t stream) {
  const float* x   = (const float*)d_in[0];
  const float* Wq  = (const float*)d_in[1];
  const float* bq  = (const float*)d_in[2];
  const float* Wk  = (const float*)d_in[3];
  const float* bk  = (const float*)d_in[4];
  const float* Wv  = (const float*)d_in[5];
  const float* bv  = (const float*)d_in[6];
  const float* W1  = (const float*)d_in[7];
  const float* b1  = (const float*)d_in[8];
  const float* W2  = (const float*)d_in[9];
  const float* b2  = (const float*)d_in[10];
  const float* g1  = (const float*)d_in[11];
  const float* be1 = (const float*)d_in[12];
  const float* g2  = (const float*)d_in[13];
  const float* be2 = (const float*)d_in[14];
  float* out = (float*)d_out;
  char* ws = (char*)d_ws;

  float* xpe  = (float*)(ws + OFF_XPE_F32);
  bf16*  xpeb = (bf16*)(ws + OFF_XPE_B);
  bf16*  Qb   = (bf16*)(ws + OFF_Q);
  bf16*  Kb   = (bf16*)(ws + OFF_K);
  bf16*  VT   = (bf16*)(ws + OFF_VT);
  bf16*  T1   = (bf16*)(ws + OFF_T1);
  float* attn = (float*)(ws + OFF_ATTN);
  float* h    = (float*)(ws + OFF_H);
  bf16*  hb   = (bf16*)(ws + OFF_XPE_B);
  float* Y    = (float*)(ws + OFF_ATTN);
  bf16*  WqkvT = (bf16*)(ws + OFF_WQKVT);
  bf16*  W1T  = (bf16*)(ws + OFF_W1T);
  bf16*  W2T  = (bf16*)(ws + OFF_W2T);

  const dim3 tb(32, 8);
  transpose_kernel<<<dim3(EMBED / 32, EMBED / 32), tb, 0, stream>>>(Wq, WqkvT, EMBED, EMBED);
  transpose_kernel<<<dim3(EMBED / 32, EMBED / 32), tb, 0, stream>>>(Wk, WqkvT + (size_t)EMBED * EMBED, EMBED, EMBED);
  transpose_kernel<<<dim3(EMBED / 32, EMBED / 32), tb, 0, stream>>>(Wv, WqkvT + 2ull * EMBED * EMBED, EMBED, EMBED);
  transpose_kernel<<<dim3(FFDIM / 32, EMBED / 32), tb, 0, stream>>>(W1, W1T, EMBED, FFDIM);
  transpose_kernel<<<dim3(EMBED / 32, FFDIM / 32), tb, 0, stream>>>(W2, W2T, FFDIM, EMBED);

  pe_add_kernel<<<(SEQ * 512) / 256, 256, 0, stream>>>(x, xpe, xpeb);

  // fused QKV projection (N = 3072)
  gemm_kernel<6><<<dim3(3072 / BN, MTOK / BM), 256, 0, stream>>>(
      xpeb, WqkvT, bq, Qb, EMBED, EMBED, bk, bv, Kb, VT);

  // fused flash attention
  flash_kernel<<<256, 512, 0, stream>>>(Qb, Kb, VT, attn);

  // h = LN(attn + xpe)
  ln_kernel<<<MTOK, 256, 0, stream>>>(attn, xpe, g1, be1, h, hb);

  // FF1: relu(h @ W1 + b1)
  gemm_kernel<3><<<dim3(FFDIM / BN, MTOK / BM), 256, 0, stream>>>(
      hb, W1T, b1, T1, EMBED, FFDIM, nullptr, nullptr, nullptr, nullptr);
  // FF2: T1 @ W2 + b2
  gemm_kernel<4><<<dim3(EMBED / BN, MTOK / BM), 256, 0, stream>>>(
      T1, W2T, b2, Y, FFDIM, EMBED, nullptr, nullptr, nullptr, nullptr);

  // out = LN(Y + h)
  ln_kernel<<<MTOK, 256, 0, stream>>>(Y, h, g2, be2, out, nullptr);
}

// Round 4
// 480.760 us; speedup vs baseline: 1.1807x; 1.1807x over previous
//
#include <hip/hip_runtime.h>
#include <hip/hip_bf16.h>
#include <cmath>
#include <cstdint>

typedef __bf16 bf16;
typedef __bf16 bf16x8 __attribute__((ext_vector_type(8)));
typedef __bf16 bf16x4 __attribute__((ext_vector_type(4)));
typedef float  f32x4  __attribute__((ext_vector_type(4)));

#define EMBED 1024
#define FFDIM 4096
#define BATCH 4
#define SEQ   2048
#define MTOK  (BATCH*SEQ)

// ---------------- workspace layout ----------------
static constexpr size_t OFF_XPE_F32 = 0;              // 32MB f32
static constexpr size_t OFF_XPE_B   = 32ull << 20;    // 16MB bf16; reused as h_bf16
static constexpr size_t OFF_Q       = 48ull << 20;    // 16MB bf16
static constexpr size_t OFF_K       = 64ull << 20;    // 16MB bf16
static constexpr size_t OFF_VT      = 80ull << 20;    // 16MB bf16 [4][1024][2048]
static constexpr size_t OFF_T1      = 96ull << 20;    // 64MB bf16 [8192][4096]
static constexpr size_t OFF_ATTN    = 160ull << 20;   // 32MB f32; reused as Y f32
static constexpr size_t OFF_H       = 192ull << 20;   // 32MB f32
static constexpr size_t OFF_WQT     = 224ull << 20;   // 2MB bf16 each
static constexpr size_t OFF_WKT     = 226ull << 20;
static constexpr size_t OFF_WVT     = 228ull << 20;
static constexpr size_t OFF_W1T     = 230ull << 20;   // 8MB
static constexpr size_t OFF_W2T     = 238ull << 20;   // 8MB

// ---------------- wait/barrier primitives ----------------
#define VMCNT4 { asm volatile("s_waitcnt vmcnt(4)" ::: "memory"); __builtin_amdgcn_sched_barrier(0); }
#define VMCNT0 { asm volatile("s_waitcnt vmcnt(0)" ::: "memory"); __builtin_amdgcn_sched_barrier(0); }
#define LGKM0  { asm volatile("s_waitcnt lgkmcnt(0)" ::: "memory"); __builtin_amdgcn_sched_barrier(0); }
#define BARRAW { asm volatile("s_waitcnt lgkmcnt(0)" ::: "memory"); __builtin_amdgcn_s_barrier(); __builtin_amdgcn_sched_barrier(0); }

__device__ __forceinline__ void gload_lds16(const void* g, void* l) {
  __builtin_amdgcn_global_load_lds((const __attribute__((address_space(1))) void*)g,
                                   (__attribute__((address_space(3))) void*)l, 16, 0, 0);
}

// ---------------- PE add ----------------
__global__ __launch_bounds__(256) void pe_add_kernel(const float* __restrict__ x,
                                                     float* __restrict__ xf,
                                                     bf16* __restrict__ xb) {
  int idx  = blockIdx.x * 256 + threadIdx.x;
  int pair = idx & 511;
  int s    = idx >> 9;
  float div = __expf((float)(2 * pair) * (-9.210340371976184f / (float)EMBED));
  float ang = (float)s * div;
  float sv = sinf(ang), cv = cosf(ang);
#pragma unroll
  for (int b = 0; b < BATCH; ++b) {
    size_t base = ((size_t)(b * SEQ + s)) * EMBED + (size_t)pair * 2;
    float v0 = x[base] + sv;
    float v1 = x[base + 1] + cv;
    xf[base] = v0; xf[base + 1] = v1;
    xb[base] = (bf16)v0; xb[base + 1] = (bf16)v1;
  }
}

// ---------------- weight transpose fp32[K][N] -> bf16[N][K] ----------------
__global__ __launch_bounds__(256) void transpose_kernel(const float* __restrict__ W,
                                                        bf16* __restrict__ Wt,
                                                        int K, int N) {
  __shared__ float tile[32][33];
  int nb = blockIdx.x * 32, kb = blockIdx.y * 32;
  int tx = threadIdx.x, ty = threadIdx.y;   // 32x8
#pragma unroll
  for (int i = 0; i < 32; i += 8)
    tile[ty + i][tx] = W[(size_t)(kb + ty + i) * N + nb + tx];
  __syncthreads();
#pragma unroll
  for (int i = 0; i < 32; i += 8)
    Wt[(size_t)(nb + ty + i) * K + kb + tx] = (bf16)tile[tx][ty + i];
}

// ---------------- GEMM: C[M,N] = A[M,K] @ Bt[N,K]^T ----------------
// EPI 0: bf16 +bias   EPI 1: bf16 +bias scatter->VT   EPI 3: bf16 +bias relu   EPI 4: f32 +bias
#define BM 128
#define BN 128
#define BK 64

template <int EPI>
__global__ __launch_bounds__(256) void gemm_kernel(
    const bf16* __restrict__ A, const bf16* __restrict__ B,
    const float* __restrict__ bias, void* __restrict__ out, int K, int ldo) {
  __shared__ __align__(16) bf16 sA[BM][BK];
  __shared__ __align__(16) bf16 sB[BN][BK];

  // T1: bijective XCD-chunked swizzle + grouped raster
  const int gx = gridDim.x, gy = gridDim.y;
  int id = blockIdx.x + gx * blockIdx.y;
  const int n  = gx * gy;
  const int q  = n >> 3, r = n & 7;
  const int xcd = id & 7, pos = id >> 3;
  int lid = (xcd < r ? xcd * (q + 1) : r * (q + 1) + (xcd - r) * q) + pos;
  const int G = 16;
  const int ngrp = G * gy;
  const int grp = lid / ngrp;
  const int within = lid - grp * ngrp;
  const int gw = min(G, gx - grp * G);
  const int tx = grp * G + within % gw;
  const int ty = within / gw;

  const int tid  = threadIdx.x;
  const int wave = tid >> 6;
  const int lane = tid & 63;
  const int wm = wave >> 1, wn = wave & 1;
  const int rowBase = ty * BM;
  const int colBase = tx * BN;

  const int rA = tid >> 3;
  const int srcSlot = (tid & 7) ^ (rA & 7);
  const bf16* gA = A + (size_t)(rowBase + rA) * K + srcSlot * 8;
  const bf16* gB = B + (size_t)(colBase + rA) * K + srcSlot * 8;
  char* lA = (char*)&sA[0][0] + wave * 1024;
  char* lB = (char*)&sB[0][0] + wave * 1024;

  const f32x4 zero4 = {0.f, 0.f, 0.f, 0.f};
  f32x4 acc[4][4];
#pragma unroll
  for (int i = 0; i < 4; ++i)
#pragma unroll
    for (int j = 0; j < 4; ++j) acc[i][j] = zero4;

  const int lr = lane & 15;
  const int lx = lane & 7;
  const int q4 = lane >> 4;
  const char* bA = (const char*)&sA[0][0];
  const char* bB = (const char*)&sB[0][0];

  for (int kt = 0; kt < K; kt += BK) {
#pragma unroll
    for (int p = 0; p < 4; ++p) {
      gload_lds16(gA + (size_t)(p * 32) * K + kt, lA + p * 4096);
      gload_lds16(gB + (size_t)(p * 32) * K + kt, lB + p * 4096);
    }
    __syncthreads();
#pragma unroll
    for (int kk = 0; kk < 2; ++kk) {
      bf16x8 fa[4], fb[4];
      const int slot = kk * 4 + q4;
      const int sws = (slot ^ lx) << 4;
#pragma unroll
      for (int i = 0; i < 4; ++i)
        fa[i] = *(const bf16x8*)(bA + (wm * 64 + i * 16 + lr) * 128 + sws);
#pragma unroll
      for (int j = 0; j < 4; ++j)
        fb[j] = *(const bf16x8*)(bB + (wn * 64 + j * 16 + lr) * 128 + sws);
#pragma unroll
      for (int i = 0; i < 4; ++i)
#pragma unroll
        for (int j = 0; j < 4; ++j)
          acc[i][j] = __builtin_amdgcn_mfma_f32_16x16x32_bf16(fa[i], fb[j], acc[i][j], 0, 0, 0);
    }
    __syncthreads();
  }

  // epilogue: C/D col = lane&15, row = (lane>>4)*4 + reg
  const int lrow4 = (lane >> 4) * 4;
#pragma unroll
  for (int j = 0; j < 4; ++j) {
    const int col = colBase + wn * 64 + j * 16 + lr;
    const float bv = bias[col];
#pragma unroll
    for (int i = 0; i < 4; ++i) {
      const int row0 = rowBase + wm * 64 + i * 16 + lrow4;
      if constexpr (EPI == 1) {
        const int b_ = row0 >> 11;
        const int s_ = row0 & (SEQ - 1);
        bf16x4 pv;
#pragma unroll
        for (int rr = 0; rr < 4; ++rr) pv[rr] = (bf16)(acc[i][j][rr] + bv);
        *(bf16x4*)((bf16*)out + ((size_t)b_ * EMBED + col) * SEQ + s_) = pv;
      } else {
#pragma unroll
        for (int rr = 0; rr < 4; ++rr) {
          const int row = row0 + rr;
          const float v = acc[i][j][rr] + bv;
          if constexpr (EPI == 0) {
            ((bf16*)out)[(size_t)row * ldo + col] = (bf16)v;
          } else if constexpr (EPI == 3) {
            ((bf16*)out)[(size_t)row * ldo + col] = (bf16)(v > 0.f ? v : 0.f);
          } else if constexpr (EPI == 4) {
            ((float*)out)[(size_t)row * ldo + col] = v;
          }
        }
      }
    }
  }
}

// ---------------- fused flash attention v2 ----------------
// 256 blocks (1/CU), 8 waves. QBLK=32 q-rows/block; per kv-iter 256 kv (32/wave).
// Per-wave async pipelines: K and V staged via global_load_lds into per-wave
// double-buffered 4KB slices with counted vmcnt(4); raw barriers (no vmcnt drain).
#define QBLK 32

// K slice: [32 kv][64 d]  (rows of 128B, 8 slots)
__device__ __forceinline__ void stage_k(const bf16* g, char* l, int lane) {
#pragma unroll
  for (int c = 0; c < 4; ++c) {
    const int row = c * 8 + (lane >> 3);
    const int sl  = (lane & 7) ^ (row & 7);
    gload_lds16(g + (size_t)row * EMBED + sl * 8, l + c * 1024);
  }
}
// V slice: [16 d][128 kv]  (rows of 256B, 16 slots)
__device__ __forceinline__ void stage_v(const bf16* g, char* l, int lane) {
#pragma unroll
  for (int c = 0; c < 4; ++c) {
    const int row = c * 4 + (lane >> 4);
    const int sl  = (lane & 15) ^ (row & 7);
    gload_lds16(g + (size_t)row * SEQ + sl * 8, l + c * 1024);
  }
}

__global__ __launch_bounds__(512) void flash_kernel(const bf16* __restrict__ Qg,
                                                    const bf16* __restrict__ Kg,
                                                    const bf16* __restrict__ Vt,
                                                    float* __restrict__ attn) {
  __shared__ __align__(16) bf16 Qs[QBLK * EMBED];   // 64KB, XOR-swizzled chunks
  __shared__ __align__(16) char KVs[8][8192];       // per-wave dbuf slices, 64KB
  __shared__ __align__(16) bf16 Ps[QBLK * 256];     // 16KB [q][kv], swizzled
  __shared__ float red[32 * 8];                     // [q][wave]
  __shared__ float rsum[32 * 8];

  const int bid = blockIdx.x;
  const int lid = (bid & 7) * 32 + (bid >> 3);      // XCD-chunked
  const int b   = lid >> 6;
  const int qt  = lid & 63;
  const bf16* Qp = Qg + ((size_t)b * SEQ + qt * QBLK) * EMBED;
  const bf16* Kp = Kg + (size_t)b * SEQ * EMBED;
  const bf16* Vp = Vt + (size_t)b * EMBED * SEQ;

  const int tid = threadIdx.x;
  const int w = tid >> 6, lane = tid & 63;
  const int lr = lane & 15, g = lane >> 4;
  char* kvb = KVs[w];

  // stage Q (pre-swizzled source, linear LDS dest)
#pragma unroll
  for (int p = 0; p < 8; ++p) {
    const int row = p * 4 + (w >> 1);
    const int sl = ((w & 1) * 64 + lane) ^ (row & 7);
    gload_lds16(Qp + (size_t)row * EMBED + sl * 8, (char*)Qs + p * 8192 + w * 1024);
  }

  const f32x4 zero4 = {0.f, 0.f, 0.f, 0.f};
  f32x4 o[8][2];
#pragma unroll
  for (int ss = 0; ss < 8; ++ss) { o[ss][0] = zero4; o[ss][1] = zero4; }
  float m0 = -1e30f, m1 = -1e30f, l0 = 0.f, l1 = 0.f;

  VMCNT0; BARRAW;                                   // Q resident

  // K prologue (it=0, t=0 -> buf0)
  stage_k(Kp + (size_t)(w * 32) * EMBED, kvb, lane);

  for (int it = 0; it < 8; ++it) {
    const int kv0 = it * 256;
    f32x4 s00 = zero4, s01 = zero4, s10 = zero4, s11 = zero4;

    // ---- QK^T: 16 d-steps, per-wave pipelined ----
#pragma unroll
    for (int t = 0; t < 16; ++t) {
      if (t < 15) {
        LGKM0;
        stage_k(Kp + (size_t)(kv0 + w * 32) * EMBED + (t + 1) * 64,
                kvb + ((t + 1) & 1) * 4096, lane);
        VMCNT4;
      } else { VMCNT0; }
      const char* kb = kvb + (t & 1) * 4096;
#pragma unroll
      for (int kk = 0; kk < 2; ++kk) {
        const int swa = (((kk * 4 + g) ^ (lr & 7)) << 4);
        bf16x8 a0 = *(const bf16x8*)(kb + lr * 128 + swa);
        bf16x8 a1 = *(const bf16x8*)(kb + (16 + lr) * 128 + swa);
        const int swq = (((t * 8 + kk * 4 + g) ^ (lr & 7)) << 4);
        bf16x8 b0 = *(const bf16x8*)((char*)Qs + lr * 2048 + swq);
        bf16x8 b1 = *(const bf16x8*)((char*)Qs + (16 + lr) * 2048 + swq);
        s00 = __builtin_amdgcn_mfma_f32_16x16x32_bf16(a0, b0, s00, 0, 0, 0);
        s01 = __builtin_amdgcn_mfma_f32_16x16x32_bf16(a0, b1, s01, 0, 0, 0);
        s10 = __builtin_amdgcn_mfma_f32_16x16x32_bf16(a1, b0, s10, 0, 0, 0);
        s11 = __builtin_amdgcn_mfma_f32_16x16x32_bf16(a1, b1, s11, 0, 0, 0);
      }
    }

    // V prologue (u=0 -> buf0); flies across the softmax barriers
    LGKM0;
    stage_v(Vp + (size_t)(w * 128) * SEQ + kv0, kvb, lane);

    // ---- softmax (per-lane m/l state; no serial sections) ----
    float mx0 = -1e30f, mx1 = -1e30f;
#pragma unroll
    for (int rr = 0; rr < 4; ++rr) {
      s00[rr] *= 0.03125f; s01[rr] *= 0.03125f; s10[rr] *= 0.03125f; s11[rr] *= 0.03125f;
      mx0 = fmaxf(mx0, fmaxf(s00[rr], s10[rr]));
      mx1 = fmaxf(mx1, fmaxf(s01[rr], s11[rr]));
    }
    mx0 = fmaxf(mx0, __shfl_xor(mx0, 16)); mx0 = fmaxf(mx0, __shfl_xor(mx0, 32));
    mx1 = fmaxf(mx1, __shfl_xor(mx1, 16)); mx1 = fmaxf(mx1, __shfl_xor(mx1, 32));
    if (g == 0) { red[lr * 8 + w] = mx0; red[(16 + lr) * 8 + w] = mx1; }
    BARRAW;                                         // (1) red ready
    f32x4 ra = *(const f32x4*)&red[lr * 8];
    f32x4 rb = *(const f32x4*)&red[lr * 8 + 4];
    f32x4 rc = *(const f32x4*)&red[(16 + lr) * 8];
    f32x4 rd = *(const f32x4*)&red[(16 + lr) * 8 + 4];
    float cm0 = fmaxf(fmaxf(fmaxf(ra[0], ra[1]), fmaxf(ra[2], ra[3])),
                      fmaxf(fmaxf(rb[0], rb[1]), fmaxf(rb[2], rb[3])));
    float cm1 = fmaxf(fmaxf(fmaxf(rc[0], rc[1]), fmaxf(rc[2], rc[3])),
                      fmaxf(fmaxf(rd[0], rd[1]), fmaxf(rd[2], rd[3])));
    const float nm0 = fmaxf(m0, cm0), nm1 = fmaxf(m1, cm1);
    const float al0 = __expf(m0 - nm0), al1 = __expf(m1 - nm1);
    m0 = nm0; m1 = nm1;

    float sum0 = 0.f, sum1 = 0.f;
#pragma unroll
    for (int mm = 0; mm < 2; ++mm) {
      const f32x4 sa = mm ? s10 : s00;
      const f32x4 sb = mm ? s11 : s01;
      bf16x4 pk0, pk1;
#pragma unroll
      for (int rr = 0; rr < 4; ++rr) {
        float p0 = __expf(sa[rr] - m0);
        float p1 = __expf(sb[rr] - m1);
        sum0 += p0; sum1 += p1;
        pk0[rr] = (bf16)p0; pk1[rr] = (bf16)p1;
      }
      const int slot = w * 4 + mm * 2 + (g >> 1);
      const int off = ((g & 1) << 3);
      *(bf16x4*)((char*)Ps + lr * 512 + ((slot ^ (lr & 7)) << 4) + off) = pk0;
      *(bf16x4*)((char*)Ps + (16 + lr) * 512 + ((slot ^ (lr & 7)) << 4) + off) = pk1;
    }
    sum0 += __shfl_xor(sum0, 16); sum0 += __shfl_xor(sum0, 32);
    sum1 += __shfl_xor(sum1, 16); sum1 += __shfl_xor(sum1, 32);
    if (g == 0) { rsum[lr * 8 + w] = sum0; rsum[(16 + lr) * 8 + w] = sum1; }
    // rescale O
#pragma unroll
    for (int ss = 0; ss < 8; ++ss)
#pragma unroll
      for (int rr = 0; rr < 4; ++rr) { o[ss][0][rr] *= al0; o[ss][1][rr] *= al1; }
    BARRAW;                                         // (2) Ps + rsum ready
    {
      f32x4 ta = *(const f32x4*)&rsum[lr * 8];
      f32x4 tb = *(const f32x4*)&rsum[lr * 8 + 4];
      f32x4 tc = *(const f32x4*)&rsum[(16 + lr) * 8];
      f32x4 td = *(const f32x4*)&rsum[(16 + lr) * 8 + 4];
      l0 = l0 * al0 + (ta[0] + ta[1] + ta[2] + ta[3]) + (tb[0] + tb[1] + tb[2] + tb[3]);
      l1 = l1 * al1 + (tc[0] + tc[1] + tc[2] + tc[3]) + (td[0] + td[1] + td[2] + td[3]);
    }

    // ---- PV: 16 sub-steps (2 kv-halves x 8 d-tiles), per-wave pipelined ----
    bf16x8 pb[4][2];
#pragma unroll
    for (int u = 0; u < 16; ++u) {
      if (u < 15) {
        LGKM0;
        stage_v(Vp + (size_t)(w * 128 + ((u + 1) & 7) * 16) * SEQ + kv0 + ((u + 1) >> 3) * 128,
                kvb + ((u + 1) & 1) * 4096, lane);
        VMCNT4;
      } else { VMCNT0; }
      if ((u & 7) == 0) {
        const int h = u >> 3;
#pragma unroll
        for (int kk = 0; kk < 4; ++kk) {
          const int slot = h * 16 + kk * 4 + g;
          pb[kk][0] = *(const bf16x8*)((char*)Ps + lr * 512 + ((slot ^ (lr & 7)) << 4));
          pb[kk][1] = *(const bf16x8*)((char*)Ps + (16 + lr) * 512 + ((slot ^ (lr & 7)) << 4));
        }
      }
      const char* vb = kvb + (u & 1) * 4096;
      const int ss = u & 7;
#pragma unroll
      for (int kk = 0; kk < 4; ++kk) {
        bf16x8 av = *(const bf16x8*)(vb + lr * 256 + ((((kk * 4 + g) ^ (lr & 7))) << 4));
        o[ss][0] = __builtin_amdgcn_mfma_f32_16x16x32_bf16(av, pb[kk][0], o[ss][0], 0, 0, 0);
        o[ss][1] = __builtin_amdgcn_mfma_f32_16x16x32_bf16(av, pb[kk][1], o[ss][1], 0, 0, 0);
      }
    }
    LGKM0;
    if (it < 7)  // K prologue for next iter
      stage_k(Kp + (size_t)(kv0 + 256 + w * 32) * EMBED, kvb, lane);
    BARRAW;                                         // (3) Ps/red/rsum reuse fence
  }

  // ---- epilogue: per-lane regs only ----
  const float li0 = 1.0f / l0;
  const float li1 = 1.0f / l1;
  float* outb = attn + ((size_t)b * SEQ + qt * QBLK) * EMBED;
#pragma unroll
  for (int ss = 0; ss < 8; ++ss) {
    const int d = w * 128 + ss * 16 + g * 4;
    f32x4 v0, v1;
#pragma unroll
    for (int rr = 0; rr < 4; ++rr) { v0[rr] = o[ss][0][rr] * li0; v1[rr] = o[ss][1][rr] * li1; }
    *(f32x4*)(outb + (size_t)lr * EMBED + d) = v0;
    *(f32x4*)(outb + (size_t)(16 + lr) * EMBED + d) = v1;
  }
}

// ---------------- LayerNorm: out = LN(X + R) * g + b ----------------
__global__ __launch_bounds__(256) void ln_kernel(const float* __restrict__ X,
                                                 const float* __restrict__ R,
                                                 const float* __restrict__ gm,
                                                 const float* __restrict__ bt,
                                                 float* __restrict__ of,
                                                 bf16* __restrict__ ob) {
  const size_t row = blockIdx.x;
  const int t = threadIdx.x;
  float4 xv = ((const float4*)(X + row * EMBED))[t];
  float4 rv = ((const float4*)(R + row * EMBED))[t];
  float4 v;
  v.x = xv.x + rv.x; v.y = xv.y + rv.y; v.z = xv.z + rv.z; v.w = xv.w + rv.w;
  float s  = v.x + v.y + v.z + v.w;
  float ss = v.x * v.x + v.y * v.y + v.z * v.z + v.w * v.w;
#pragma unroll
  for (int o = 32; o; o >>= 1) { s += __shfl_xor(s, o); ss += __shfl_xor(ss, o); }
  __shared__ float red[8];
  const int w = t >> 6;
  if ((t & 63) == 0) { red[w] = s; red[4 + w] = ss; }
  __syncthreads();
  s  = red[0] + red[1] + red[2] + red[3];
  ss = red[4] + red[5] + red[6] + red[7];
  const float mu  = s * (1.0f / EMBED);
  const float inv = rsqrtf(ss * (1.0f / EMBED) - mu * mu + 1e-5f);
  float4 gv = ((const float4*)gm)[t];
  float4 bv = ((const float4*)bt)[t];
  float4 o4;
  o4.x = (v.x - mu) * inv * gv.x + bv.x;
  o4.y = (v.y - mu) * inv * gv.y + bv.y;
  o4.z = (v.z - mu) * inv * gv.z + bv.z;
  o4.w = (v.w - mu) * inv * gv.w + bv.w;
  if (of) ((float4*)(of + row * EMBED))[t] = o4;
  if (ob) {
    bf16x4 p;
    p[0] = (bf16)o4.x; p[1] = (bf16)o4.y; p[2] = (bf16)o4.z; p[3] = (bf16)o4.w;
    *(bf16x4*)(ob + row * EMBED + (size_t)t * 4) = p;
  }
}

// ---------------- launch ----------------
extern "C" void kernel_launch(void* const* d_in, const int* in_sizes, int n_in,
                              void* d_out, int out_size, void* d_ws, size_t ws_size,
                              hipStream_t stream) {
  const float* x   = (const float*)d_in[0];
  const float* Wq  = (const float*)d_in[1];
  const float* bq  = (const float*)d_in[2];
  const float* Wk  = (const float*)d_in[3];
  const float* bk  = (const float*)d_in[4];
  const float* Wv  = (const float*)d_in[5];
  const float* bv  = (const float*)d_in[6];
  const float* W1  = (const float*)d_in[7];
  const float* b1  = (const float*)d_in[8];
  const float* W2  = (const float*)d_in[9];
  const float* b2  = (const float*)d_in[10];
  const float* g1  = (const float*)d_in[11];
  const float* be1 = (const float*)d_in[12];
  const float* g2  = (const float*)d_in[13];
  const float* be2 = (const float*)d_in[14];
  float* out = (float*)d_out;
  char* ws = (char*)d_ws;

  float* xpe  = (float*)(ws + OFF_XPE_F32);
  bf16*  xpeb = (bf16*)(ws + OFF_XPE_B);
  bf16*  Qb   = (bf16*)(ws + OFF_Q);
  bf16*  Kb   = (bf16*)(ws + OFF_K);
  bf16*  VT   = (bf16*)(ws + OFF_VT);
  bf16*  T1   = (bf16*)(ws + OFF_T1);
  float* attn = (float*)(ws + OFF_ATTN);
  float* h    = (float*)(ws + OFF_H);
  bf16*  hb   = (bf16*)(ws + OFF_XPE_B);
  float* Y    = (float*)(ws + OFF_ATTN);
  bf16*  WqT  = (bf16*)(ws + OFF_WQT);
  bf16*  WkT  = (bf16*)(ws + OFF_WKT);
  bf16*  WvT  = (bf16*)(ws + OFF_WVT);
  bf16*  W1T  = (bf16*)(ws + OFF_W1T);
  bf16*  W2T  = (bf16*)(ws + OFF_W2T);

  const dim3 tb(32, 8);
  transpose_kernel<<<dim3(EMBED / 32, EMBED / 32), tb, 0, stream>>>(Wq, WqT, EMBED, EMBED);
  transpose_kernel<<<dim3(EMBED / 32, EMBED / 32), tb, 0, stream>>>(Wk, WkT, EMBED, EMBED);
  transpose_kernel<<<dim3(EMBED / 32, EMBED / 32), tb, 0, stream>>>(Wv, WvT, EMBED, EMBED);
  transpose_kernel<<<dim3(FFDIM / 32, EMBED / 32), tb, 0, stream>>>(W1, W1T, EMBED, FFDIM);
  transpose_kernel<<<dim3(EMBED / 32, FFDIM / 32), tb, 0, stream>>>(W2, W2T, FFDIM, EMBED);

  pe_add_kernel<<<(SEQ * 512) / 256, 256, 0, stream>>>(x, xpe, xpeb);

  // QKV projections (3 separate, round-2 proven config)
  gemm_kernel<0><<<dim3(EMBED / BN, MTOK / BM), 256, 0, stream>>>(xpeb, WqT, bq, Qb, EMBED, EMBED);
  gemm_kernel<0><<<dim3(EMBED / BN, MTOK / BM), 256, 0, stream>>>(xpeb, WkT, bk, Kb, EMBED, EMBED);
  gemm_kernel<1><<<dim3(EMBED / BN, MTOK / BM), 256, 0, stream>>>(xpeb, WvT, bv, VT, EMBED, 0);

  // fused flash attention v2
  flash_kernel<<<256, 512, 0, stream>>>(Qb, Kb, VT, attn);

  // h = LN(attn + xpe)
  ln_kernel<<<MTOK, 256, 0, stream>>>(attn, xpe, g1, be1, h, hb);

  // FF1: relu(h @ W1 + b1)
  gemm_kernel<3><<<dim3(FFDIM / BN, MTOK / BM), 256, 0, stream>>>(hb, W1T, b1, T1, EMBED, FFDIM);
  // FF2: T1 @ W2 + b2
  gemm_kernel<4><<<dim3(EMBED / BN, MTOK / BM), 256, 0, stream>>>(T1, W2T, b2, Y, FFDIM, EMBED);

  // out = LN(Y + h)
  ln_kernel<<<MTOK, 256, 0, stream>>>(Y, h, g2, be2, out, nullptr);
}

// Round 5
// 393.856 us; speedup vs baseline: 1.4412x; 1.2207x over previous
//
#include <hip/hip_runtime.h>
#include <hip/hip_bf16.h>
#include <cmath>
#include <cstdint>

typedef __bf16 bf16;
typedef __bf16 bf16x8 __attribute__((ext_vector_type(8)));
typedef __bf16 bf16x4 __attribute__((ext_vector_type(4)));
typedef float  f32x4  __attribute__((ext_vector_type(4)));

#define EMBED 1024
#define FFDIM 4096
#define BATCH 4
#define SEQ   2048
#define MTOK  (BATCH*SEQ)

// ---------------- workspace layout ----------------
static constexpr size_t OFF_XPE_F32 = 0;              // 32MB f32
static constexpr size_t OFF_XPE_B   = 32ull << 20;    // 16MB bf16; reused as h_bf16
static constexpr size_t OFF_Q       = 48ull << 20;    // 16MB bf16; Q..K reused as P (32MB)
static constexpr size_t OFF_K       = 64ull << 20;    // 16MB bf16
static constexpr size_t OFF_VT      = 80ull << 20;    // 16MB bf16 [4][1024][2048]
static constexpr size_t OFF_E       = 96ull << 20;    // 64MB f32 E; reused as T1 bf16 [8192][4096]
static constexpr size_t OFF_ATTN    = 160ull << 20;   // 32MB f32; reused as Y f32
static constexpr size_t OFF_H       = 192ull << 20;   // 32MB f32
static constexpr size_t OFF_WQT     = 224ull << 20;   // 2MB bf16 each
static constexpr size_t OFF_WKT     = 226ull << 20;
static constexpr size_t OFF_WVT     = 228ull << 20;
static constexpr size_t OFF_W1T     = 230ull << 20;   // 8MB
static constexpr size_t OFF_W2T     = 238ull << 20;   // 8MB

// ---------------- wait/barrier primitives ----------------
#define VMCNT6 { asm volatile("s_waitcnt vmcnt(6)" ::: "memory"); __builtin_amdgcn_sched_barrier(0); }
#define VMCNT0 { asm volatile("s_waitcnt vmcnt(0)" ::: "memory"); __builtin_amdgcn_sched_barrier(0); }
#define BARRAW { asm volatile("s_waitcnt lgkmcnt(0)" ::: "memory"); __builtin_amdgcn_s_barrier(); __builtin_amdgcn_sched_barrier(0); }

__device__ __forceinline__ void gload_lds16(const void* g, void* l) {
  __builtin_amdgcn_global_load_lds((const __attribute__((address_space(1))) void*)g,
                                   (__attribute__((address_space(3))) void*)l, 16, 0, 0);
}

// ---------------- PE add ----------------
__global__ __launch_bounds__(256) void pe_add_kernel(const float* __restrict__ x,
                                                     float* __restrict__ xf,
                                                     bf16* __restrict__ xb) {
  int idx  = blockIdx.x * 256 + threadIdx.x;
  int pair = idx & 511;
  int s    = idx >> 9;
  float div = __expf((float)(2 * pair) * (-9.210340371976184f / (float)EMBED));
  float ang = (float)s * div;
  float sv = sinf(ang), cv = cosf(ang);
#pragma unroll
  for (int b = 0; b < BATCH; ++b) {
    size_t base = ((size_t)(b * SEQ + s)) * EMBED + (size_t)pair * 2;
    float v0 = x[base] + sv;
    float v1 = x[base + 1] + cv;
    xf[base] = v0; xf[base + 1] = v1;
    xb[base] = (bf16)v0; xb[base + 1] = (bf16)v1;
  }
}

// ---------------- weight transpose fp32[K][N] -> bf16[N][K] ----------------
__global__ __launch_bounds__(256) void transpose_kernel(const float* __restrict__ W,
                                                        bf16* __restrict__ Wt,
                                                        int K, int N) {
  __shared__ float tile[32][33];
  int nb = blockIdx.x * 32, kb = blockIdx.y * 32;
  int tx = threadIdx.x, ty = threadIdx.y;   // 32x8
#pragma unroll
  for (int i = 0; i < 32; i += 8)
    tile[ty + i][tx] = W[(size_t)(kb + ty + i) * N + nb + tx];
  __syncthreads();
#pragma unroll
  for (int i = 0; i < 32; i += 8)
    Wt[(size_t)(nb + ty + i) * K + kb + tx] = (bf16)tile[tx][ty + i];
}

// ---------------- gemm3: C[M,N] = A[M,K] @ Bt[N,K]^T, triple-buffered counted pipeline ----
// BM=256, BN=128, BK=64, 512 threads (8 waves, 4M x 2N, wave-out 64x64).
// LDS: A 3x32KB + B 3x16KB = 144KB. Stage tile T+2 during tile T; vmcnt(6)+raw
// barrier per tile (loads for T+1/T+2 stay in flight across the barrier).
// EPI 0: bf16 +bias   EPI 1: bf16 +bias scatter->VT   EPI 2: f32 *scale (batched)
// EPI 3: bf16 +bias relu   EPI 4: f32 +bias
#define BM3 256
#define BN3 128
#define BK3 64

template <int EPI>
__global__ __launch_bounds__(512, 2) void gemm3_kernel(
    const bf16* __restrict__ A, const bf16* __restrict__ B,
    const float* __restrict__ bias, void* __restrict__ out,
    int K, int ldo, long long sAz, long long sBz, long long sOz, float scale) {
  __shared__ __align__(16) char ldsA[3 * 32768];
  __shared__ __align__(16) char ldsB[3 * 16384];

  // bijective XCD-chunked swizzle (m204)
  const int gx = gridDim.x, gy = gridDim.y;
  int id = blockIdx.x + gx * (blockIdx.y + gy * blockIdx.z);
  const int nwg = gx * gy * gridDim.z;
  const int qd = nwg >> 3, rm = nwg & 7;
  const int xcd = id & 7, pos = id >> 3;
  const int lid = (xcd < rm ? xcd * (qd + 1) : rm * (qd + 1) + (xcd - rm) * qd) + pos;
  const int per = gx * gy;
  const int tz = lid / per;
  const int s2 = lid - tz * per;
  const int ty = s2 / gx;
  const int tx = s2 - ty * gx;

  A += (size_t)tz * sAz;
  B += (size_t)tz * sBz;

  const int tid  = threadIdx.x;
  const int wave = tid >> 6;
  const int lane = tid & 63;
  const int wm = wave >> 1, wn = wave & 1;   // 4M x 2N
  const int rowBase = ty * BM3;
  const int colBase = tx * BN3;

  // staging: per 8KB issue, thread t covers row p*64 + (t>>3), slot t&7 (src XOR-swizzled)
  const int rS = tid >> 3;                       // 0..63
  const int srcSlot = (tid & 7) ^ (rS & 7);
  const bf16* gA = A + (size_t)(rowBase + rS) * K + srcSlot * 8;
  const bf16* gB = B + (size_t)(colBase + rS) * K + srcSlot * 8;

  auto stageA = [&](int Tt, int bufi, int p0, int p1) {
    char* dst = ldsA + bufi * 32768 + wave * 1024;
    const bf16* src = gA + (size_t)Tt * BK3;
#pragma unroll
    for (int p = 0; p < 4; ++p)
      if (p >= p0 && p < p1)
        gload_lds16(src + (size_t)(p * 64) * K, dst + p * 8192);
  };
  auto stageB = [&](int Tt, int bufi) {
    char* dst = ldsB + bufi * 16384 + wave * 1024;
    const bf16* src = gB + (size_t)Tt * BK3;
#pragma unroll
    for (int p = 0; p < 2; ++p)
      gload_lds16(src + (size_t)(p * 64) * K, dst + p * 8192);
  };

  const f32x4 zero4 = {0.f, 0.f, 0.f, 0.f};
  f32x4 acc[4][4];
#pragma unroll
  for (int i = 0; i < 4; ++i)
#pragma unroll
    for (int j = 0; j < 4; ++j) acc[i][j] = zero4;

  const int lr = lane & 15;
  const int g  = lane >> 4;
  const int nK = K / BK3;

  // prologue: tile0 -> buf0, tile1 -> buf1 (12 loads/wave); wait tile0 (oldest 6)
  stageA(0, 0, 0, 4); stageB(0, 0);
  stageA(1, 1, 0, 4); stageB(1, 1);
  VMCNT6; BARRAW;

  int cur = 0, st = 2;
  for (int T = 0; T < nK; ++T) {
    const char* bA = ldsA + cur * 32768;
    const char* bB = ldsB + cur * 16384;
    const bool pre = (T + 2 < nK);

    // fragments: A (held across both halves), B cols 0..31
    bf16x8 fa[2][4], fb[2][2];
#pragma unroll
    for (int kk = 0; kk < 2; ++kk) {
      const int sw = ((kk * 4 + g) ^ (lr & 7)) << 4;
#pragma unroll
      for (int i = 0; i < 4; ++i)
        fa[kk][i] = *(const bf16x8*)(bA + (wm * 64 + i * 16 + lr) * 128 + sw);
#pragma unroll
      for (int j = 0; j < 2; ++j)
        fb[kk][j] = *(const bf16x8*)(bB + (wn * 64 + j * 16 + lr) * 128 + sw);
    }
    if (pre) stageA(T + 2, st, 0, 3);
    __builtin_amdgcn_s_setprio(1);
#pragma unroll
    for (int kk = 0; kk < 2; ++kk)
#pragma unroll
      for (int i = 0; i < 4; ++i)
#pragma unroll
        for (int j = 0; j < 2; ++j)
          acc[i][j] = __builtin_amdgcn_mfma_f32_16x16x32_bf16(fa[kk][i], fb[kk][j], acc[i][j], 0, 0, 0);
    __builtin_amdgcn_s_setprio(0);

    // B cols 32..63
#pragma unroll
    for (int kk = 0; kk < 2; ++kk) {
      const int sw = ((kk * 4 + g) ^ (lr & 7)) << 4;
#pragma unroll
      for (int j = 0; j < 2; ++j)
        fb[kk][j] = *(const bf16x8*)(bB + (wn * 64 + (j + 2) * 16 + lr) * 128 + sw);
    }
    if (pre) { stageA(T + 2, st, 3, 4); stageB(T + 2, st); }
    __builtin_amdgcn_s_setprio(1);
#pragma unroll
    for (int kk = 0; kk < 2; ++kk)
#pragma unroll
      for (int i = 0; i < 4; ++i)
#pragma unroll
        for (int j = 0; j < 2; ++j)
          acc[i][j + 2] = __builtin_amdgcn_mfma_f32_16x16x32_bf16(fa[kk][i], fb[kk][j], acc[i][j + 2], 0, 0, 0);
    __builtin_amdgcn_s_setprio(0);

    if (pre) { VMCNT6 } else { VMCNT0 }
    BARRAW;
    cur = (cur == 2) ? 0 : cur + 1;
    st  = (st == 2) ? 0 : st + 1;
  }

  // epilogue: C/D layout col = lane&15, row = (lane>>4)*4 + reg  [m89-verified]
  const int lrow4 = g * 4;
#pragma unroll
  for (int j = 0; j < 4; ++j) {
    const int col = colBase + wn * 64 + j * 16 + lr;
    float bv = 0.f;
    if constexpr (EPI == 0 || EPI == 1 || EPI == 3 || EPI == 4) bv = bias[col];
#pragma unroll
    for (int i = 0; i < 4; ++i) {
      const int row0 = rowBase + wm * 64 + i * 16 + lrow4;
      if constexpr (EPI == 1) {
        const int b_ = row0 >> 11;
        const int s_ = row0 & (SEQ - 1);
        bf16x4 pv;
#pragma unroll
        for (int rr = 0; rr < 4; ++rr) pv[rr] = (bf16)(acc[i][j][rr] + bv);
        *(bf16x4*)((bf16*)out + ((size_t)b_ * EMBED + col) * SEQ + s_) = pv;
      } else {
#pragma unroll
        for (int rr = 0; rr < 4; ++rr) {
          const int row = row0 + rr;
          const float v = acc[i][j][rr];
          if constexpr (EPI == 0) {
            ((bf16*)out)[(size_t)row * ldo + col] = (bf16)(v + bv);
          } else if constexpr (EPI == 2) {
            ((float*)out)[(size_t)tz * sOz + (size_t)row * ldo + col] = v * scale;
          } else if constexpr (EPI == 3) {
            float t = v + bv;
            ((bf16*)out)[(size_t)row * ldo + col] = (bf16)(t > 0.f ? t : 0.f);
          } else if constexpr (EPI == 4) {
            ((float*)out)[(size_t)row * ldo + col] = v + bv;
          }
        }
      }
    }
  }
}

// ---------------- row softmax: E f32 [rows][SEQ] -> P bf16 ----------------
__global__ __launch_bounds__(256) void softmax_kernel(const float* __restrict__ E,
                                                      bf16* __restrict__ P) {
  const size_t row = blockIdx.x;
  const float* e = E + row * SEQ;
  const int t = threadIdx.x;
  float4 a = ((const float4*)e)[2 * t];
  float4 b = ((const float4*)e)[2 * t + 1];
  float m = fmaxf(fmaxf(fmaxf(a.x, a.y), fmaxf(a.z, a.w)),
                  fmaxf(fmaxf(b.x, b.y), fmaxf(b.z, b.w)));
#pragma unroll
  for (int o = 32; o; o >>= 1) m = fmaxf(m, __shfl_xor(m, o));
  __shared__ float red[8];
  const int w = t >> 6;
  if ((t & 63) == 0) red[w] = m;
  __syncthreads();
  m = fmaxf(fmaxf(red[0], red[1]), fmaxf(red[2], red[3]));
  float ex[8];
  ex[0] = __expf(a.x - m); ex[1] = __expf(a.y - m);
  ex[2] = __expf(a.z - m); ex[3] = __expf(a.w - m);
  ex[4] = __expf(b.x - m); ex[5] = __expf(b.y - m);
  ex[6] = __expf(b.z - m); ex[7] = __expf(b.w - m);
  float s = ex[0] + ex[1] + ex[2] + ex[3] + ex[4] + ex[5] + ex[6] + ex[7];
#pragma unroll
  for (int o = 32; o; o >>= 1) s += __shfl_xor(s, o);
  if ((t & 63) == 0) red[4 + w] = s;
  __syncthreads();
  s = red[4] + red[5] + red[6] + red[7];
  const float inv = 1.0f / s;
  bf16x8 pv;
#pragma unroll
  for (int q = 0; q < 8; ++q) pv[q] = (bf16)(ex[q] * inv);
  *(bf16x8*)(P + row * SEQ + (size_t)t * 8) = pv;
}

// ---------------- LayerNorm: out = LN(X + R) * g + b ----------------
__global__ __launch_bounds__(256) void ln_kernel(const float* __restrict__ X,
                                                 const float* __restrict__ R,
                                                 const float* __restrict__ gm,
                                                 const float* __restrict__ bt,
                                                 float* __restrict__ of,
                                                 bf16* __restrict__ ob) {
  const size_t row = blockIdx.x;
  const int t = threadIdx.x;
  float4 xv = ((const float4*)(X + row * EMBED))[t];
  float4 rv = ((const float4*)(R + row * EMBED))[t];
  float4 v;
  v.x = xv.x + rv.x; v.y = xv.y + rv.y; v.z = xv.z + rv.z; v.w = xv.w + rv.w;
  float s  = v.x + v.y + v.z + v.w;
  float ss = v.x * v.x + v.y * v.y + v.z * v.z + v.w * v.w;
#pragma unroll
  for (int o = 32; o; o >>= 1) { s += __shfl_xor(s, o); ss += __shfl_xor(ss, o); }
  __shared__ float red[8];
  const int w = t >> 6;
  if ((t & 63) == 0) { red[w] = s; red[4 + w] = ss; }
  __syncthreads();
  s  = red[0] + red[1] + red[2] + red[3];
  ss = red[4] + red[5] + red[6] + red[7];
  const float mu  = s * (1.0f / EMBED);
  const float inv = rsqrtf(ss * (1.0f / EMBED) - mu * mu + 1e-5f);
  float4 gv = ((const float4*)gm)[t];
  float4 bv = ((const float4*)bt)[t];
  float4 o4;
  o4.x = (v.x - mu) * inv * gv.x + bv.x;
  o4.y = (v.y - mu) * inv * gv.y + bv.y;
  o4.z = (v.z - mu) * inv * gv.z + bv.z;
  o4.w = (v.w - mu) * inv * gv.w + bv.w;
  if (of) ((float4*)(of + row * EMBED))[t] = o4;
  if (ob) {
    bf16x4 p;
    p[0] = (bf16)o4.x; p[1] = (bf16)o4.y; p[2] = (bf16)o4.z; p[3] = (bf16)o4.w;
    *(bf16x4*)(ob + row * EMBED + (size_t)t * 4) = p;
  }
}

// ---------------- launch ----------------
extern "C" void kernel_launch(void* const* d_in, const int* in_sizes, int n_in,
                              void* d_out, int out_size, void* d_ws, size_t ws_size,
                              hipStream_t stream) {
  const float* x   = (const float*)d_in[0];
  const float* Wq  = (const float*)d_in[1];
  const float* bq  = (const float*)d_in[2];
  const float* Wk  = (const float*)d_in[3];
  const float* bk  = (const float*)d_in[4];
  const float* Wv  = (const float*)d_in[5];
  const float* bv  = (const float*)d_in[6];
  const float* W1  = (const float*)d_in[7];
  const float* b1  = (const float*)d_in[8];
  const float* W2  = (const float*)d_in[9];
  const float* b2  = (const float*)d_in[10];
  const float* g1  = (const float*)d_in[11];
  const float* be1 = (const float*)d_in[12];
  const float* g2  = (const float*)d_in[13];
  const float* be2 = (const float*)d_in[14];
  float* out = (float*)d_out;
  char* ws = (char*)d_ws;

  float* xpe  = (float*)(ws + OFF_XPE_F32);
  bf16*  xpeb = (bf16*)(ws + OFF_XPE_B);
  bf16*  Qb   = (bf16*)(ws + OFF_Q);
  bf16*  Kb   = (bf16*)(ws + OFF_K);
  bf16*  VT   = (bf16*)(ws + OFF_VT);
  float* E    = (float*)(ws + OFF_E);
  bf16*  P    = (bf16*)(ws + OFF_Q);     // reuse Q+K region after QK^T
  bf16*  T1   = (bf16*)(ws + OFF_E);     // reuse E region after softmax
  float* attn = (float*)(ws + OFF_ATTN);
  float* h    = (float*)(ws + OFF_H);
  bf16*  hb   = (bf16*)(ws + OFF_XPE_B); // reuse xpe_bf16 region
  float* Y    = (float*)(ws + OFF_ATTN); // reuse attn region
  bf16*  WqT  = (bf16*)(ws + OFF_WQT);
  bf16*  WkT  = (bf16*)(ws + OFF_WKT);
  bf16*  WvT  = (bf16*)(ws + OFF_WVT);
  bf16*  W1T  = (bf16*)(ws + OFF_W1T);
  bf16*  W2T  = (bf16*)(ws + OFF_W2T);

  const dim3 tb(32, 8);
  transpose_kernel<<<dim3(EMBED / 32, EMBED / 32), tb, 0, stream>>>(Wq, WqT, EMBED, EMBED);
  transpose_kernel<<<dim3(EMBED / 32, EMBED / 32), tb, 0, stream>>>(Wk, WkT, EMBED, EMBED);
  transpose_kernel<<<dim3(EMBED / 32, EMBED / 32), tb, 0, stream>>>(Wv, WvT, EMBED, EMBED);
  transpose_kernel<<<dim3(FFDIM / 32, EMBED / 32), tb, 0, stream>>>(W1, W1T, EMBED, FFDIM);
  transpose_kernel<<<dim3(EMBED / 32, FFDIM / 32), tb, 0, stream>>>(W2, W2T, FFDIM, EMBED);

  pe_add_kernel<<<(SEQ * 512) / 256, 256, 0, stream>>>(x, xpe, xpeb);

  // QKV projections (M=8192, N=1024 -> 8x32 = 256 blocks each)
  gemm3_kernel<0><<<dim3(EMBED / BN3, MTOK / BM3), 512, 0, stream>>>(
      xpeb, WqT, bq, Qb, EMBED, EMBED, 0, 0, 0, 1.0f);
  gemm3_kernel<0><<<dim3(EMBED / BN3, MTOK / BM3), 512, 0, stream>>>(
      xpeb, WkT, bk, Kb, EMBED, EMBED, 0, 0, 0, 1.0f);
  gemm3_kernel<1><<<dim3(EMBED / BN3, MTOK / BM3), 512, 0, stream>>>(
      xpeb, WvT, bv, VT, EMBED, 0, 0, 0, 0, 1.0f);

  // energy = Q @ K^T / 32  (batched; 16x8x4 = 512 blocks)
  gemm3_kernel<2><<<dim3(SEQ / BN3, SEQ / BM3, BATCH), 512, 0, stream>>>(
      Qb, Kb, nullptr, E, EMBED, SEQ,
      (long long)SEQ * EMBED, (long long)SEQ * EMBED, (long long)SEQ * SEQ, 0.03125f);

  softmax_kernel<<<BATCH * SEQ, 256, 0, stream>>>(E, P);

  // attn = P @ V  (batched; 8x8x4 = 256 blocks)
  gemm3_kernel<2><<<dim3(EMBED / BN3, SEQ / BM3, BATCH), 512, 0, stream>>>(
      P, VT, nullptr, attn, SEQ, EMBED,
      (long long)SEQ * SEQ, (long long)EMBED * SEQ, (long long)SEQ * EMBED, 1.0f);

  // h = LN(attn + xpe)
  ln_kernel<<<MTOK, 256, 0, stream>>>(attn, xpe, g1, be1, h, hb);

  // FF1: relu(h @ W1 + b1)  (32x32 = 1024 blocks)
  gemm3_kernel<3><<<dim3(FFDIM / BN3, MTOK / BM3), 512, 0, stream>>>(
      hb, W1T, b1, T1, EMBED, FFDIM, 0, 0, 0, 1.0f);
  // FF2: T1 @ W2 + b2  (8x32 = 256 blocks)
  gemm3_kernel<4><<<dim3(EMBED / BN3, MTOK / BM3), 512, 0, stream>>>(
      T1, W2T, b2, Y, FFDIM, EMBED, 0, 0, 0, 1.0f);

  // out = LN(Y + h)
  ln_kernel<<<MTOK, 256, 0, stream>>>(Y, h, g2, be2, out, nullptr);
}